// Round 1
// baseline (4789.485 us; speedup 1.0000x reference)
//
#include <hip/hip_runtime.h>
#include <math.h>

#define TP 65  // padded LDS stride per row (64 edges + 1)

// ---------------- LDS layouts (float offsets) ----------------
// edge kernel
#define EA    0                    // 96 rows : v -> vi -> ev_lin -> vi_o
#define EB    (EA + 96*TP)         // 96 rows : ev -> nv_g -> y_v -> ov_pre
#define EDD   (EB + 96*TP)         // 64 rows : es -> ses
#define EEB   (EDD + 64*TP)        // 128 rows: cat(norm|s) -> d -> ns_g -> y_s -> os
#define ESM   (EEB + 128*TP)       // 32 rows : gate -> e2n -> norm_o
#define ESM2  (ESM + 32*TP)        // 32 rows : n2e -> gate_o
#define ECUT  (ESM2 + 32*TP)       // 64 floats: cutoff C per edge
#define EIDXO (ECUT + 64)          // 64 ints : gathered node index
#define EDGE_LDS_FLOATS (EIDXO + 64)
#define EDGE_LDS_BYTES  (EDGE_LDS_FLOATS*4)

// node kernel
#define NA   0                     // 96 rows : v -> vi
#define NEB  (NA + 96*TP)          // 160 rows: cat = [norm(32) | s(128)]
#define NDD  (NEB + 160*TP)        // 128 rows: out_s
#define NSMB (NDD + 128*TP)        // 32 rows : gate
#define NODE_LDS_FLOATS (NSMB + 32*TP)
#define NODE_LDS_BYTES  (NODE_LDS_FLOATS*4)

__device__ __forceinline__ float sigmoidf_(float z) {
    return 1.0f / (1.0f + expf(-z));
}

// =====================================================================
// Node kernel: gvlinear(node_s, node_v) -> ns_ws [N,128], nv_ws [N,96]
// =====================================================================
__global__ __launch_bounds__(512)
void node_kernel(const float* __restrict__ node_s, const float* __restrict__ node_v,
                 const float* __restrict__ Wv1, const float* __restrict__ Wv2,
                 const float* __restrict__ Ws,  const float* __restrict__ Wg,
                 const float* __restrict__ bg,
                 float* __restrict__ ns_ws, float* __restrict__ nv_ws, int N)
{
    extern __shared__ float L[];
    const int t = threadIdx.x;
    const int e = t & 63;
    const int w = __builtin_amdgcn_readfirstlane(t >> 6);
    const size_t n0 = (size_t)blockIdx.x * 64;
    const int valid = (int)min((size_t)64, (size_t)N - n0);

    // ---- stage 0: load v -> A (transposed [dim][node]), s -> E rows 32..159
#pragma unroll
    for (int r = 0; r < 3; r++) {
        int f4 = t + 512*r;                 // 1536 float4 = 64*96 floats
        int flat = f4*4;
        int ee = flat/96, dd = flat - ee*96;
        size_t row = n0 + (size_t)ee; if (row >= (size_t)N) row = (size_t)N-1;
        const float4 v4 = *(const float4*)(node_v + row*96 + dd);
        L[NA+(dd+0)*TP+ee]=v4.x; L[NA+(dd+1)*TP+ee]=v4.y;
        L[NA+(dd+2)*TP+ee]=v4.z; L[NA+(dd+3)*TP+ee]=v4.w;
    }
#pragma unroll
    for (int r = 0; r < 4; r++) {
        int f4 = t + 512*r;                 // 2048 float4 = 64*128 floats
        int flat = f4*4;
        int ee = flat >> 7, kk = flat & 127;
        size_t row = n0 + (size_t)ee; if (row >= (size_t)N) row = (size_t)N-1;
        const float4 v4 = *(const float4*)(node_s + row*128 + kk);
        L[NEB+(32+kk+0)*TP+ee]=v4.x; L[NEB+(32+kk+1)*TP+ee]=v4.y;
        L[NEB+(32+kk+2)*TP+ee]=v4.z; L[NEB+(32+kk+3)*TP+ee]=v4.w;
    }
    __syncthreads();

    // ---- G1: vi = Wv1 @ v   (A in place via regs+barrier)
    {
        float a[4][3];
#pragma unroll
        for (int j=0;j<4;j++){ a[j][0]=0.f; a[j][1]=0.f; a[j][2]=0.f; }
        const float* Wp = Wv1 + (w*4)*32;
        for (int i=0;i<32;i++){
            float x0=L[NA+(i*3+0)*TP+e], x1=L[NA+(i*3+1)*TP+e], x2=L[NA+(i*3+2)*TP+e];
#pragma unroll
            for (int j=0;j<4;j++){
                float wv = Wp[j*32+i];
                a[j][0]=fmaf(wv,x0,a[j][0]); a[j][1]=fmaf(wv,x1,a[j][1]); a[j][2]=fmaf(wv,x2,a[j][2]);
            }
        }
        __syncthreads();
#pragma unroll
        for (int j=0;j<4;j++){
            int h=w*4+j;
            L[NA+(h*3+0)*TP+e]=a[j][0]; L[NA+(h*3+1)*TP+e]=a[j][1]; L[NA+(h*3+2)*TP+e]=a[j][2];
        }
    }
    __syncthreads();

    // ---- norm -> E rows 0..31
    for (int idx=t; idx<2048; idx+=512){
        int h=idx>>6, ee=idx&63;
        float x0=L[NA+(h*3+0)*TP+ee], x1=L[NA+(h*3+1)*TP+ee], x2=L[NA+(h*3+2)*TP+ee];
        L[NEB+h*TP+ee]=sqrtf(x0*x0+x1*x1+x2*x2);
    }
    __syncthreads();

    // ---- G2: out_s = Ws @ cat (K=160) -> D + global ns_ws
    {
        float a[16];
#pragma unroll
        for (int j=0;j<16;j++) a[j]=0.f;
        const float* Wp = Ws + (size_t)(w*16)*160;
        for (int k=0;k<160;k++){
            float x = L[NEB+k*TP+e];
#pragma unroll
            for (int j=0;j<16;j++) a[j]=fmaf(Wp[j*160+k],x,a[j]);
        }
#pragma unroll
        for (int j=0;j<16;j++) L[NDD+(w*16+j)*TP+e]=a[j];
        if (e < valid){
            float* po = ns_ws + (n0+(size_t)e)*128 + w*16;
#pragma unroll
            for (int q=0;q<4;q++){
                *(float4*)(po + q*4) = make_float4(a[q*4+0],a[q*4+1],a[q*4+2],a[q*4+3]);
            }
        }
    }
    __syncthreads();

    // ---- G3: gate = sigmoid(Wg @ out_s + bg) -> SM
    {
        float a[4]={0.f,0.f,0.f,0.f};
        const float* Wp = Wg + (w*4)*128;
        for (int k=0;k<128;k++){
            float x=L[NDD+k*TP+e];
#pragma unroll
            for (int j=0;j<4;j++) a[j]=fmaf(Wp[j*128+k],x,a[j]);
        }
#pragma unroll
        for (int j=0;j<4;j++){
            L[NSMB+(w*4+j)*TP+e]=sigmoidf_(a[j]+bg[w*4+j]);
        }
    }
    __syncthreads();

    // ---- G4: out_v = gate * (Wv2 @ vi) -> global nv_ws
    {
        float a[4][3];
#pragma unroll
        for (int j=0;j<4;j++){ a[j][0]=0.f; a[j][1]=0.f; a[j][2]=0.f; }
        const float* Wp = Wv2 + (w*4)*32;
        for (int i=0;i<32;i++){
            float x0=L[NA+(i*3+0)*TP+e], x1=L[NA+(i*3+1)*TP+e], x2=L[NA+(i*3+2)*TP+e];
#pragma unroll
            for (int j=0;j<4;j++){
                float wv = Wp[j*32+i];
                a[j][0]=fmaf(wv,x0,a[j][0]); a[j][1]=fmaf(wv,x1,a[j][1]); a[j][2]=fmaf(wv,x2,a[j][2]);
            }
        }
        if (e < valid){
            float vals[12];
#pragma unroll
            for (int j=0;j<4;j++){
                float g=L[NSMB+(w*4+j)*TP+e];
                vals[j*3+0]=g*a[j][0]; vals[j*3+1]=g*a[j][1]; vals[j*3+2]=g*a[j][2];
            }
            float* pv = nv_ws + (n0+(size_t)e)*96 + w*12;
#pragma unroll
            for (int q=0;q<3;q++){
                *(float4*)(pv + q*4) = make_float4(vals[q*4+0],vals[q*4+1],vals[q*4+2],vals[q*4+3]);
            }
        }
    }
}

// =====================================================================
// Edge kernel: full fused per-edge pipeline
// =====================================================================
__global__ __launch_bounds__(512)
void edge_kernel(const float* __restrict__ edge_s_g, const float* __restrict__ edge_v_g,
                 const int* __restrict__ eidx_g, const float* __restrict__ dist_g,
                 const float* __restrict__ eWv1, const float* __restrict__ eWv2,
                 const float* __restrict__ eWs,  const float* __restrict__ eWg,
                 const float* __restrict__ ebg,  const float* __restrict__ eWd,
                 const float* __restrict__ scaW, const float* __restrict__ scab,
                 const float* __restrict__ e2nW, const float* __restrict__ e2nb,
                 const float* __restrict__ n2eW, const float* __restrict__ n2eb,
                 const float* __restrict__ evnW, const float* __restrict__ evnb,
                 const float* __restrict__ oWv1, const float* __restrict__ oWv2,
                 const float* __restrict__ oWs,  const float* __restrict__ oWg,
                 const float* __restrict__ obg,
                 const float* __restrict__ ns_ws, const float* __restrict__ nv_ws,
                 float* __restrict__ outS, float* __restrict__ outV, int E)
{
    extern __shared__ float L[];
    int* LI = (int*)&L[EIDXO];
    const int t = threadIdx.x;
    const int e = t & 63;
    const int w = __builtin_amdgcn_readfirstlane(t >> 6);
    const size_t e0 = (size_t)blockIdx.x * 64;
    const int valid = (int)min((size_t)64, (size_t)E - e0);
    const float PI_F = 3.14159265358979323846f;

    // ---- stage 0: loads
#pragma unroll
    for (int r = 0; r < 3; r++) {
        int f4 = t + 512*r;
        int flat = f4*4;
        int ee = flat/96, dd = flat - ee*96;
        size_t row = e0 + (size_t)ee; if (row >= (size_t)E) row = (size_t)E-1;
        const float4 v4 = *(const float4*)(edge_v_g + row*96 + dd);
        L[EA+(dd+0)*TP+ee]=v4.x; L[EA+(dd+1)*TP+ee]=v4.y;
        L[EA+(dd+2)*TP+ee]=v4.z; L[EA+(dd+3)*TP+ee]=v4.w;
    }
#pragma unroll
    for (int r = 0; r < 2; r++) {
        int f4 = t + 512*r;
        int flat = f4*4;
        int ee = flat>>6, kk = flat & 63;
        size_t row = e0 + (size_t)ee; if (row >= (size_t)E) row = (size_t)E-1;
        const float4 v4 = *(const float4*)(edge_s_g + row*64 + kk);
        L[EEB+(32+kk+0)*TP+ee]=v4.x; L[EEB+(32+kk+1)*TP+ee]=v4.y;
        L[EEB+(32+kk+2)*TP+ee]=v4.z; L[EEB+(32+kk+3)*TP+ee]=v4.w;
    }
    if (t < 64) {
        size_t row = e0 + (size_t)t; if (row >= (size_t)E) row = (size_t)E-1;
        LI[t] = eidx_g[row];
        float dd = dist_g[row];
        float c = 0.5f*(cosf(dd * (PI_F/10.0f)) + 1.0f);
        c = (dd >= 0.0f && dd <= 10.0f) ? c : 0.0f;
        L[ECUT + t] = c;
    }
    __syncthreads();

    // ---- G1: vi = eWv1 @ v  (A in place via regs+barrier)
    {
        float a[4][3];
#pragma unroll
        for (int j=0;j<4;j++){ a[j][0]=0.f; a[j][1]=0.f; a[j][2]=0.f; }
        const float* Wp = eWv1 + (w*4)*32;
        for (int i=0;i<32;i++){
            float x0=L[EA+(i*3+0)*TP+e], x1=L[EA+(i*3+1)*TP+e], x2=L[EA+(i*3+2)*TP+e];
#pragma unroll
            for (int j=0;j<4;j++){
                float wv = Wp[j*32+i];
                a[j][0]=fmaf(wv,x0,a[j][0]); a[j][1]=fmaf(wv,x1,a[j][1]); a[j][2]=fmaf(wv,x2,a[j][2]);
            }
        }
        __syncthreads();
#pragma unroll
        for (int j=0;j<4;j++){
            int h=w*4+j;
            L[EA+(h*3+0)*TP+e]=a[j][0]; L[EA+(h*3+1)*TP+e]=a[j][1]; L[EA+(h*3+2)*TP+e]=a[j][2];
        }
    }
    __syncthreads();

    // ---- norm -> E rows 0..31 (cat = [norm | s])
    for (int idx=t; idx<2048; idx+=512){
        int h=idx>>6, ee=idx&63;
        float x0=L[EA+(h*3+0)*TP+ee], x1=L[EA+(h*3+1)*TP+ee], x2=L[EA+(h*3+2)*TP+ee];
        L[EEB+h*TP+ee]=sqrtf(x0*x0+x1*x1+x2*x2);
    }
    __syncthreads();

    // ---- G2: es = eWs @ cat (K=96, Nout=64) -> D
    {
        float a[8];
#pragma unroll
        for (int j=0;j<8;j++) a[j]=0.f;
        const float* Wp = eWs + (w*8)*96;
        for (int k=0;k<96;k++){
            float x = L[EEB+k*TP+e];
#pragma unroll
            for (int j=0;j<8;j++) a[j]=fmaf(Wp[j*96+k],x,a[j]);
        }
#pragma unroll
        for (int j=0;j<8;j++) L[EDD+(w*8+j)*TP+e]=a[j];
    }
    __syncthreads();

    // ---- G3: gate = sigmoid(eWg @ es + ebg) -> SM
    {
        float a[4]={0.f,0.f,0.f,0.f};
        const float* Wp = eWg + (w*4)*64;
        for (int k=0;k<64;k++){
            float x = L[EDD+k*TP+e];
#pragma unroll
            for (int j=0;j<4;j++) a[j]=fmaf(Wp[j*64+k],x,a[j]);
        }
#pragma unroll
        for (int j=0;j<4;j++) L[ESM+(w*4+j)*TP+e]=sigmoidf_(a[j]+ebg[w*4+j]);
    }
    __syncthreads();

    // ---- G4: ev = gate * (eWv2 @ vi) -> B
    {
        float a[4][3];
#pragma unroll
        for (int j=0;j<4;j++){ a[j][0]=0.f; a[j][1]=0.f; a[j][2]=0.f; }
        const float* Wp = eWv2 + (w*4)*32;
        for (int i=0;i<32;i++){
            float x0=L[EA+(i*3+0)*TP+e], x1=L[EA+(i*3+1)*TP+e], x2=L[EA+(i*3+2)*TP+e];
#pragma unroll
            for (int j=0;j<4;j++){
                float wv = Wp[j*32+i];
                a[j][0]=fmaf(wv,x0,a[j][0]); a[j][1]=fmaf(wv,x1,a[j][1]); a[j][2]=fmaf(wv,x2,a[j][2]);
            }
        }
#pragma unroll
        for (int j=0;j<4;j++){
            int o=w*4+j;
            float g = L[ESM+o*TP+e];
            L[EB+(o*3+0)*TP+e]=g*a[j][0]; L[EB+(o*3+1)*TP+e]=g*a[j][1]; L[EB+(o*3+2)*TP+e]=g*a[j][2];
        }
    }
    __syncthreads();

    // ---- G5: d = eWd @ ev -> E rows 0..95 (cat dead)
    {
        float a[4][3];
#pragma unroll
        for (int j=0;j<4;j++){ a[j][0]=0.f; a[j][1]=0.f; a[j][2]=0.f; }
        const float* Wp = eWd + (w*4)*32;
        for (int i=0;i<32;i++){
            float x0=L[EB+(i*3+0)*TP+e], x1=L[EB+(i*3+1)*TP+e], x2=L[EB+(i*3+2)*TP+e];
#pragma unroll
            for (int j=0;j<4;j++){
                float wv = Wp[j*32+i];
                a[j][0]=fmaf(wv,x0,a[j][0]); a[j][1]=fmaf(wv,x1,a[j][1]); a[j][2]=fmaf(wv,x2,a[j][2]);
            }
        }
#pragma unroll
        for (int j=0;j<4;j++){
            int o=w*4+j;
            L[EEB+(o*3+0)*TP+e]=a[j][0]; L[EEB+(o*3+1)*TP+e]=a[j][1]; L[EEB+(o*3+2)*TP+e]=a[j][2];
        }
    }
    __syncthreads();

    // ---- VNLeakyReLU on ev (B in place), leaky on es (D in place)
    for (int idx=t; idx<2048; idx+=512){
        int o=idx>>6, ee=idx&63;
        float x0=L[EB+(o*3+0)*TP+ee], x1=L[EB+(o*3+1)*TP+ee], x2=L[EB+(o*3+2)*TP+ee];
        float d0=L[EEB+(o*3+0)*TP+ee], d1=L[EEB+(o*3+1)*TP+ee], d2=L[EEB+(o*3+2)*TP+ee];
        float dot=x0*d0+x1*d1+x2*d2;
        float dn =d0*d0+d1*d1+d2*d2;
        float s_ = dot/(dn + 1e-6f);
        float y0,y1,y2;
        if (dot >= 0.f){ y0=x0; y1=x1; y2=x2; }
        else { y0=x0-s_*d0; y1=x1-s_*d1; y2=x2-s_*d2; }
        L[EB+(o*3+0)*TP+ee]=0.01f*x0+0.99f*y0;
        L[EB+(o*3+1)*TP+ee]=0.01f*x1+0.99f*y1;
        L[EB+(o*3+2)*TP+ee]=0.01f*x2+0.99f*y2;
    }
    for (int idx=t; idx<4096; idx+=512){
        int k=idx>>6, ee=idx&63;
        float x=L[EDD+k*TP+ee];
        L[EDD+k*TP+ee]=(x>=0.f)? x : 0.01f*x;
    }
    __syncthreads();

    // ---- G6: ev_lin = evnW @ ev + evnb -> A (vi dead)
    {
        float a[4][3];
#pragma unroll
        for (int j=0;j<4;j++){ a[j][0]=0.f; a[j][1]=0.f; a[j][2]=0.f; }
        const float* Wp = evnW + (w*4)*32;
        for (int i=0;i<32;i++){
            float x0=L[EB+(i*3+0)*TP+e], x1=L[EB+(i*3+1)*TP+e], x2=L[EB+(i*3+2)*TP+e];
#pragma unroll
            for (int j=0;j<4;j++){
                float wv = Wp[j*32+i];
                a[j][0]=fmaf(wv,x0,a[j][0]); a[j][1]=fmaf(wv,x1,a[j][1]); a[j][2]=fmaf(wv,x2,a[j][2]);
            }
        }
#pragma unroll
        for (int j=0;j<4;j++){
            int o=w*4+j; float b=evnb[o];
            L[EA+(o*3+0)*TP+e]=a[j][0]+b; L[EA+(o*3+1)*TP+e]=a[j][1]+b; L[EA+(o*3+2)*TP+e]=a[j][2]+b;
        }
    }
    __syncthreads();

    // ---- gather: ns_g -> E rows 0..127 (d dead), nv_g -> B (ev dead)
    {
        int eL = t>>3, kl = t&7;
        size_t j = (size_t)LI[eL];
        const float* np_ = ns_ws + j*128;
#pragma unroll
        for (int i4=0;i4<4;i4++){
            int k = kl*16 + i4*4;
            float4 v4 = *(const float4*)(np_ + k);
            L[EEB+(k+0)*TP+eL]=v4.x; L[EEB+(k+1)*TP+eL]=v4.y;
            L[EEB+(k+2)*TP+eL]=v4.z; L[EEB+(k+3)*TP+eL]=v4.w;
        }
        const float* vp_ = nv_ws + j*96;
#pragma unroll
        for (int i4=0;i4<3;i4++){
            int k = kl*12 + i4*4;
            float4 v4 = *(const float4*)(vp_ + k);
            L[EB+(k+0)*TP+eL]=v4.x; L[EB+(k+1)*TP+eL]=v4.y;
            L[EB+(k+2)*TP+eL]=v4.z; L[EB+(k+3)*TP+eL]=v4.w;
        }
    }
    __syncthreads();

    // ---- G8: e2n -> SM (gate dead) ; G9: n2e -> SM2
    {
        float a[4]={0.f,0.f,0.f,0.f};
        const float* Wp = e2nW + (w*4)*64;
        for (int k=0;k<64;k++){
            float x=L[EDD+k*TP+e];
#pragma unroll
            for (int j=0;j<4;j++) a[j]=fmaf(Wp[j*64+k],x,a[j]);
        }
#pragma unroll
        for (int j=0;j<4;j++) L[ESM+(w*4+j)*TP+e]=a[j]+e2nb[w*4+j];

        float b[4]={0.f,0.f,0.f,0.f};
        const float* Wp2 = n2eW + (w*4)*128;
        for (int k=0;k<128;k++){
            float x=L[EEB+k*TP+e];
#pragma unroll
            for (int j=0;j<4;j++) b[j]=fmaf(Wp2[j*128+k],x,b[j]);
        }
#pragma unroll
        for (int j=0;j<4;j++) L[ESM2+(w*4+j)*TP+e]=b[j]+n2eb[w*4+j];
    }
    __syncthreads();

    // ---- y_v = e2n*nv_g + n2e*ev_lin -> B in place (A dead after)
    for (int idx=t; idx<2048; idx+=512){
        int o=idx>>6, ee=idx&63;
        float g1=L[ESM+o*TP+ee], g2=L[ESM2+o*TP+ee];
#pragma unroll
        for (int c=0;c<3;c++){
            L[EB+(o*3+c)*TP+ee] = g1*L[EB+(o*3+c)*TP+ee] + g2*L[EA+(o*3+c)*TP+ee];
        }
    }
    __syncthreads();

    // ---- G7: y_s = ns_g * (scaW @ ses + scab) -> E in place
    {
        float a[16];
#pragma unroll
        for (int j=0;j<16;j++) a[j]=0.f;
        const float* Wp = scaW + (size_t)(w*16)*64;
        for (int k=0;k<64;k++){
            float x=L[EDD+k*TP+e];
#pragma unroll
            for (int j=0;j<16;j++) a[j]=fmaf(Wp[j*64+k],x,a[j]);
        }
#pragma unroll
        for (int j=0;j<16;j++){
            int o=w*16+j;
            float ns_=L[EEB+o*TP+e];
            L[EEB+o*TP+e]=ns_*(a[j]+scab[o]);
        }
    }
    __syncthreads();

    // ---- G10: vi_o = oWv1 @ y_v -> A
    {
        float a[4][3];
#pragma unroll
        for (int j=0;j<4;j++){ a[j][0]=0.f; a[j][1]=0.f; a[j][2]=0.f; }
        const float* Wp = oWv1 + (w*4)*32;
        for (int i=0;i<32;i++){
            float x0=L[EB+(i*3+0)*TP+e], x1=L[EB+(i*3+1)*TP+e], x2=L[EB+(i*3+2)*TP+e];
#pragma unroll
            for (int j=0;j<4;j++){
                float wv = Wp[j*32+i];
                a[j][0]=fmaf(wv,x0,a[j][0]); a[j][1]=fmaf(wv,x1,a[j][1]); a[j][2]=fmaf(wv,x2,a[j][2]);
            }
        }
#pragma unroll
        for (int j=0;j<4;j++){
            int h=w*4+j;
            L[EA+(h*3+0)*TP+e]=a[j][0]; L[EA+(h*3+1)*TP+e]=a[j][1]; L[EA+(h*3+2)*TP+e]=a[j][2];
        }
    }
    __syncthreads();

    // ---- norm_o -> SM (e2n dead)
    for (int idx=t; idx<2048; idx+=512){
        int h=idx>>6, ee=idx&63;
        float x0=L[EA+(h*3+0)*TP+ee], x1=L[EA+(h*3+1)*TP+ee], x2=L[EA+(h*3+2)*TP+ee];
        L[ESM+h*TP+ee]=sqrtf(x0*x0+x1*x1+x2*x2);
    }
    __syncthreads();

    // ---- G13: ov_pre = oWv2 @ vi_o -> B (y_v dead)
    {
        float a[4][3];
#pragma unroll
        for (int j=0;j<4;j++){ a[j][0]=0.f; a[j][1]=0.f; a[j][2]=0.f; }
        const float* Wp = oWv2 + (w*4)*32;
        for (int i=0;i<32;i++){
            float x0=L[EA+(i*3+0)*TP+e], x1=L[EA+(i*3+1)*TP+e], x2=L[EA+(i*3+2)*TP+e];
#pragma unroll
            for (int j=0;j<4;j++){
                float wv = Wp[j*32+i];
                a[j][0]=fmaf(wv,x0,a[j][0]); a[j][1]=fmaf(wv,x1,a[j][1]); a[j][2]=fmaf(wv,x2,a[j][2]);
            }
        }
#pragma unroll
        for (int j=0;j<4;j++){
            int o=w*4+j;
            L[EB+(o*3+0)*TP+e]=a[j][0]; L[EB+(o*3+1)*TP+e]=a[j][1]; L[EB+(o*3+2)*TP+e]=a[j][2];
        }
    }
    __syncthreads();

    // ---- G11: os = oWs @ [norm_o(32) ; y_s(128)] -> E in place (regs+barrier)
    {
        float a[16];
#pragma unroll
        for (int j=0;j<16;j++) a[j]=0.f;
        const float* Wp = oWs + (size_t)(w*16)*160;
        for (int k=0;k<32;k++){
            float x=L[ESM+k*TP+e];
#pragma unroll
            for (int j=0;j<16;j++) a[j]=fmaf(Wp[j*160+k],x,a[j]);
        }
        for (int k=0;k<128;k++){
            float x=L[EEB+k*TP+e];
#pragma unroll
            for (int j=0;j<16;j++) a[j]=fmaf(Wp[j*160+32+k],x,a[j]);
        }
        __syncthreads();
#pragma unroll
        for (int j=0;j<16;j++) L[EEB+(w*16+j)*TP+e]=a[j];
    }
    __syncthreads();

    // ---- G12: gate_o = sigmoid(oWg @ os + obg) -> SM2 (n2e dead)
    {
        float a[4]={0.f,0.f,0.f,0.f};
        const float* Wp = oWg + (w*4)*128;
        for (int k=0;k<128;k++){
            float x=L[EEB+k*TP+e];
#pragma unroll
            for (int j=0;j<4;j++) a[j]=fmaf(Wp[j*128+k],x,a[j]);
        }
#pragma unroll
        for (int j=0;j<4;j++) L[ESM2+(w*4+j)*TP+e]=sigmoidf_(a[j]+obg[w*4+j]);
    }
    __syncthreads();

    // ---- outputs with cutoff
    if (e < valid) {
        float c = L[ECUT + e];
        float* po = outS + (e0+(size_t)e)*128 + w*16;
#pragma unroll
        for (int q=0;q<4;q++){
            float4 v4;
            v4.x = L[EEB+(w*16+q*4+0)*TP+e]*c;
            v4.y = L[EEB+(w*16+q*4+1)*TP+e]*c;
            v4.z = L[EEB+(w*16+q*4+2)*TP+e]*c;
            v4.w = L[EEB+(w*16+q*4+3)*TP+e]*c;
            *(float4*)(po + q*4) = v4;
        }
        float vals[12];
#pragma unroll
        for (int j=0;j<4;j++){
            int o=w*4+j;
            float g=L[ESM2+o*TP+e]*c;
            vals[j*3+0]=g*L[EB+(o*3+0)*TP+e];
            vals[j*3+1]=g*L[EB+(o*3+1)*TP+e];
            vals[j*3+2]=g*L[EB+(o*3+2)*TP+e];
        }
        float* pv = outV + (e0+(size_t)e)*96 + w*12;
#pragma unroll
        for (int q=0;q<3;q++){
            *(float4*)(pv + q*4) = make_float4(vals[q*4+0],vals[q*4+1],vals[q*4+2],vals[q*4+3]);
        }
    }
}

// =====================================================================
extern "C" void kernel_launch(void* const* d_in, const int* in_sizes, int n_in,
                              void* d_out, int out_size, void* d_ws, size_t ws_size,
                              hipStream_t stream) {
    const float* node_s = (const float*)d_in[0];
    const float* node_v = (const float*)d_in[1];
    const float* edge_s = (const float*)d_in[2];
    const float* edge_v = (const float*)d_in[3];
    const int*   eidx   = (const int*)d_in[4];
    const float* dist   = (const float*)d_in[5];
    const float* nWv1=(const float*)d_in[6],  *nWv2=(const float*)d_in[7];
    const float* nWs =(const float*)d_in[8],  *nWg =(const float*)d_in[9],  *nbg=(const float*)d_in[10];
    const float* eWv1=(const float*)d_in[11], *eWv2=(const float*)d_in[12];
    const float* eWs =(const float*)d_in[13], *eWg =(const float*)d_in[14], *ebg=(const float*)d_in[15];
    const float* eWd =(const float*)d_in[16];
    const float* scaW=(const float*)d_in[17], *scab=(const float*)d_in[18];
    const float* e2nW=(const float*)d_in[19], *e2nb=(const float*)d_in[20];
    const float* n2eW=(const float*)d_in[21], *n2eb=(const float*)d_in[22];
    const float* evnW=(const float*)d_in[23], *evnb=(const float*)d_in[24];
    const float* oWv1=(const float*)d_in[25], *oWv2=(const float*)d_in[26];
    const float* oWs =(const float*)d_in[27], *oWg =(const float*)d_in[28], *obg=(const float*)d_in[29];

    const int N = in_sizes[0] / 128;
    const int E = in_sizes[2] / 64;

    float* ns_ws = (float*)d_ws;
    float* nv_ws = ns_ws + (size_t)N*128;
    float* outS  = (float*)d_out;
    float* outV  = outS + (size_t)E*128;

    hipFuncSetAttribute((const void*)node_kernel, hipFuncAttributeMaxDynamicSharedMemorySize, NODE_LDS_BYTES);
    hipFuncSetAttribute((const void*)edge_kernel, hipFuncAttributeMaxDynamicSharedMemorySize, EDGE_LDS_BYTES);

    const int nb = (N + 63) / 64;
    node_kernel<<<nb, 512, NODE_LDS_BYTES, stream>>>(node_s, node_v, nWv1, nWv2, nWs, nWg, nbg,
                                                     ns_ws, nv_ws, N);

    const int eb = (E + 63) / 64;
    edge_kernel<<<eb, 512, EDGE_LDS_BYTES, stream>>>(edge_s, edge_v, eidx, dist,
                                                     eWv1, eWv2, eWs, eWg, ebg, eWd,
                                                     scaW, scab, e2nW, e2nb, n2eW, n2eb, evnW, evnb,
                                                     oWv1, oWv2, oWs, oWg, obg,
                                                     ns_ws, nv_ws, outS, outV, E);
}